// Round 10
// baseline (10725.851 us; speedup 1.0000x reference)
//
#include <hip/hip_runtime.h>
#include <hip/hip_bf16.h>
#include <stdint.h>

#define SEQ 2048
#define IN_DIM 2048
#define HID 4096
#define CONCAT 6144
#define OUT_DIM 2048

typedef __attribute__((ext_vector_type(8))) short s8v;
typedef __attribute__((ext_vector_type(4))) float f4v;

#define SENT 0xFFFFFFFFu   // sentinel; sigmoid output in (0,1) never matches
#define ROT_BUDGET 150     // pipelined-poll rotations before falling back (~10 expected)
#define FB_BUDGET 20000    // fallback spin budget: fail loud (absmax), never hang

// ---------------- ws layout (bytes) ----------------
// Z:     [0, 33554432)            float Z[SEQ][HID]
// hbuf:  [33554432, 67108864)     float hbuf[SEQ][HID]   (rows 1..2047 used)
// Xb:    [33554432, +8388608)     bf16  (overlaps hbuf; dead before memset re-arms sentinel)
// Wxb:   [41943040, +16777216)    bf16
// total required: 67,108,864 B

// ---------------- K1: pack bf16 ----------------
__global__ __launch_bounds__(256) void k1_prep(const float* __restrict__ X,
                                               const float* __restrict__ Wi2h,
                                               __hip_bfloat16* __restrict__ Xb,
                                               __hip_bfloat16* __restrict__ Wxb) {
  int gid = blockIdx.x * blockDim.x + threadIdx.x;
  int stride = gridDim.x * blockDim.x;
  for (int i = gid; i < SEQ * IN_DIM; i += stride)
    Xb[i] = __float2bfloat16(X[i]);
  for (int i = gid; i < HID * IN_DIM; i += stride) {
    int r = i >> 11, c = i & (IN_DIM - 1);
    Wxb[i] = __float2bfloat16(Wi2h[(long long)r * CONCAT + c]);
  }
}

// ---------------- K2: Z = Xb @ Wxb^T + b  (bf16 MFMA, 64x64 tiles) ----------------
__global__ __launch_bounds__(256) void k2_zgemm(const __hip_bfloat16* __restrict__ Xb,
                                                const __hip_bfloat16* __restrict__ Wxb,
                                                const float* __restrict__ bias,
                                                float* __restrict__ Z) {
  __shared__ __align__(16) __hip_bfloat16 As[64][40];
  __shared__ __align__(16) __hip_bfloat16 Bs[64][40];
  const int bm = blockIdx.x & 31;
  const int bn = blockIdx.x >> 5;
  const int tid = threadIdx.x;
  const int wv = tid >> 6, l = tid & 63;
  const int wr = (wv >> 1) * 32, wc = (wv & 1) * 32;
  const int fr = l & 15, fko = (l >> 4) * 8;

  f4v acc[2][2] = {};
  const int r = tid >> 2, cc = (tid & 3) * 8;
  const __hip_bfloat16* ga = Xb + (long long)(bm * 64 + r) * IN_DIM + cc;
  const __hip_bfloat16* gb = Wxb + (long long)(bn * 64 + r) * IN_DIM + cc;

  for (int k0 = 0; k0 < IN_DIM; k0 += 32) {
    *(s8v*)&As[r][cc] = *(const s8v*)(ga + k0);
    *(s8v*)&Bs[r][cc] = *(const s8v*)(gb + k0);
    __syncthreads();
    s8v a0 = *(const s8v*)&As[wr + fr][fko];
    s8v a1 = *(const s8v*)&As[wr + 16 + fr][fko];
    s8v b0 = *(const s8v*)&Bs[wc + fr][fko];
    s8v b1 = *(const s8v*)&Bs[wc + 16 + fr][fko];
    acc[0][0] = __builtin_amdgcn_mfma_f32_16x16x32_bf16(a0, b0, acc[0][0], 0, 0, 0);
    acc[0][1] = __builtin_amdgcn_mfma_f32_16x16x32_bf16(a0, b1, acc[0][1], 0, 0, 0);
    acc[1][0] = __builtin_amdgcn_mfma_f32_16x16x32_bf16(a1, b0, acc[1][0], 0, 0, 0);
    acc[1][1] = __builtin_amdgcn_mfma_f32_16x16x32_bf16(a1, b1, acc[1][1], 0, 0, 0);
    __syncthreads();
  }
#pragma unroll
  for (int fm = 0; fm < 2; ++fm)
#pragma unroll
    for (int fn = 0; fn < 2; ++fn)
#pragma unroll
      for (int i = 0; i < 4; ++i) {
        int row = bm * 64 + wr + fm * 16 + (l >> 4) * 4 + i;
        int col = bn * 64 + wc + fn * 16 + fr;
        Z[(long long)row * HID + col] = acc[fm][fn][i] + bias[col];
      }
}

// ---------------- K3: persistent-weight recurrence (cooperative) ----------------
// 256 WGs x 512 thr. WG w owns h rows [16w,16w+16). Wave v owns K-slice [512v,512(v+1)).
// Lane l: k = 512v + 64j + l (j=0..7); weights Wreg[16][8] pinned.
// Sync: DATA-AS-FLAG at the MALL. Poll = 3 phase-shifted batches of 8
// global_load_lds_dword (aux=17: SC0|SC1, MALL-coherent) + naked counted
// s_waitcnt vmcnt(16). LDS destination => NO async register hazard (the R9 bug:
// compiler phi-copies of asm-load dest regs captured stale data). Checks read LDS
// via normal compiler ds_read (synchronous SSA). Raw lgkmcnt(0)+s_barrier instead of
// __syncthreads so in-flight poll loads are never force-drained; vmcnt arithmetic:
// entry = leftovers(<=16)+z(1)+store(<=1)+24 fresh; vmcnt(16) always completes
// exactly through the target batch (in-order VMEM retirement).
// Fallback: proven R8 compiler-atomic poll after ROT_BUDGET (worst case ~R8 perf).
__global__ __launch_bounds__(512, 1) void k3_rnn(const float* __restrict__ Wi2h,
                                                 const float* __restrict__ Z,
                                                 float* __restrict__ hbuf) {
  const int w = blockIdx.x;
  const int tid = threadIdx.x;
  const int v = tid >> 6;
  const int l = tid & 63;
  const int rowbase = w * 16;
  const int kbase = v * 512 + l;

  float Wreg[16][8];
#pragma unroll
  for (int r = 0; r < 16; ++r) {
    const float* src = Wi2h + (long long)(rowbase + r) * CONCAT + IN_DIM + kbase;
#pragma unroll
    for (int j = 0; j < 8; ++j) Wreg[r][j] = src[64 * j];
  }
#pragma unroll
  for (int r = 0; r < 16; ++r)
#pragma unroll
    for (int j = 0; j < 8; ++j)
      asm volatile("" : "+v"(Wreg[r][j]));  // pin: no remat/sink into t-loop

  __shared__ uint32_t pbuf[3][8][8][64];  // [batch][wave][word j][lane] 48KB
  __shared__ float zbuf[8][64];           // z staging via global_load_lds (2KB)
  __shared__ float part[2][8][17];        // +1 pad
  const int lm = l & 15;
  const int r_mine = ((lm & 1) << 3) | ((lm & 2) << 1) | ((lm & 4) >> 1) | ((lm & 8) >> 3);

#define FMAG(uu, dd, jj)                                                          \
  if (!dd && __all((uu) != SENT)) {                                               \
    float h_ = __builtin_bit_cast(float, (uu));                                   \
    _Pragma("unroll")                                                             \
    for (int r = 0; r < 16; ++r) acc[r] = fmaf(Wreg[r][jj], h_, acc[r]);          \
    dd = true;                                                                    \
  }

#define GISSUE(RB)                                                                \
  _Pragma("unroll")                                                               \
  for (int j = 0; j < 8; ++j)                                                     \
    __builtin_amdgcn_global_load_lds(hsrc + 64 * j, &pbuf[RB][v][j][0], 4, 0, 17);

#define POLLCHK(RB)                                                               \
  asm volatile("s_waitcnt vmcnt(16)" ::: "memory");                               \
  __builtin_amdgcn_sched_barrier(0);                                              \
  {                                                                               \
    uint32_t u_;                                                                  \
    u_ = pbuf[RB][v][0][l]; FMAG(u_, d0, 0)                                       \
    u_ = pbuf[RB][v][1][l]; FMAG(u_, d1, 1)                                       \
    u_ = pbuf[RB][v][2][l]; FMAG(u_, d2, 2)                                       \
    u_ = pbuf[RB][v][3][l]; FMAG(u_, d3, 3)                                       \
    u_ = pbuf[RB][v][4][l]; FMAG(u_, d4, 4)                                       \
    u_ = pbuf[RB][v][5][l]; FMAG(u_, d5, 5)                                       \
    u_ = pbuf[RB][v][6][l]; FMAG(u_, d6, 6)                                       \
    u_ = pbuf[RB][v][7][l]; FMAG(u_, d7, 7)                                       \
  }

#define ALLD (d0 && d1 && d2 && d3 && d4 && d5 && d6 && d7)

#pragma clang loop unroll(disable)
  for (int t = 0; t < SEQ - 1; ++t) {
    // z staging via LDS (keeps compiler's tracked vmem-load set EMPTY in the loop)
    const float* zsrc = Z + (long long)t * HID + rowbase + 2 * v + (l & 1);
    __builtin_amdgcn_global_load_lds(zsrc, &zbuf[v][0], 4, 0, 0);

    float acc[16];
#pragma unroll
    for (int r = 0; r < 16; ++r) acc[r] = 0.f;
    bool d0 = false, d1 = false, d2 = false, d3 = false,
         d4 = false, d5 = false, d6 = false, d7 = false;

    if (t > 0) {
      const uint32_t* hsrc = (const uint32_t*)hbuf + (long long)t * HID + kbase;
      GISSUE(0) GISSUE(1) GISSUE(2)
      int rot = 0;
      for (;;) {
        POLLCHK(0) if (ALLD) break;
        GISSUE(0)
        POLLCHK(1) if (ALLD) break;
        GISSUE(1)
        POLLCHK(2) if (ALLD) break;
        GISSUE(2)
        if (++rot > ROT_BUDGET) break;
      }
      if (!ALLD) {
        // fallback: proven R8 compiler-atomic sentinel poll (covers aux-encoding risk)
        int spins = 0;
        for (;;) {
          uint32_t u_;
          if (!d0) { u_ = __hip_atomic_load(hsrc + 0,   __ATOMIC_RELAXED, __HIP_MEMORY_SCOPE_AGENT); FMAG(u_, d0, 0) }
          if (!d1) { u_ = __hip_atomic_load(hsrc + 64,  __ATOMIC_RELAXED, __HIP_MEMORY_SCOPE_AGENT); FMAG(u_, d1, 1) }
          if (!d2) { u_ = __hip_atomic_load(hsrc + 128, __ATOMIC_RELAXED, __HIP_MEMORY_SCOPE_AGENT); FMAG(u_, d2, 2) }
          if (!d3) { u_ = __hip_atomic_load(hsrc + 192, __ATOMIC_RELAXED, __HIP_MEMORY_SCOPE_AGENT); FMAG(u_, d3, 3) }
          if (!d4) { u_ = __hip_atomic_load(hsrc + 256, __ATOMIC_RELAXED, __HIP_MEMORY_SCOPE_AGENT); FMAG(u_, d4, 4) }
          if (!d5) { u_ = __hip_atomic_load(hsrc + 320, __ATOMIC_RELAXED, __HIP_MEMORY_SCOPE_AGENT); FMAG(u_, d5, 5) }
          if (!d6) { u_ = __hip_atomic_load(hsrc + 384, __ATOMIC_RELAXED, __HIP_MEMORY_SCOPE_AGENT); FMAG(u_, d6, 6) }
          if (!d7) { u_ = __hip_atomic_load(hsrc + 448, __ATOMIC_RELAXED, __HIP_MEMORY_SCOPE_AGENT); FMAG(u_, d7, 7) }
          if (ALLD) break;
          if (++spins > FB_BUDGET) break;  // fail loud, never hang
        }
      }
    } else {
      asm volatile("s_waitcnt vmcnt(0)" ::: "memory");  // t=0: drain zbuf load
    }

    // reduce-scatter butterfly: 16 accs across 64 lanes -> 1 row-sum per lane-of-16
#pragma unroll
    for (int i = 0; i < 8; ++i) {
      float send = (l & 1) ? acc[i] : acc[i + 8];
      float keep = (l & 1) ? acc[i + 8] : acc[i];
      acc[i] = keep + __shfl_xor(send, 1, 64);
    }
#pragma unroll
    for (int i = 0; i < 4; ++i) {
      float send = (l & 2) ? acc[i] : acc[i + 4];
      float keep = (l & 2) ? acc[i + 4] : acc[i];
      acc[i] = keep + __shfl_xor(send, 2, 64);
    }
#pragma unroll
    for (int i = 0; i < 2; ++i) {
      float send = (l & 4) ? acc[i] : acc[i + 2];
      float keep = (l & 4) ? acc[i + 2] : acc[i];
      acc[i] = keep + __shfl_xor(send, 4, 64);
    }
    {
      float send = (l & 8) ? acc[0] : acc[1];
      float keep = (l & 8) ? acc[1] : acc[0];
      acc[0] = keep + __shfl_xor(send, 8, 64);
    }
    float rsum = acc[0];
    rsum += __shfl_xor(rsum, 16, 64);
    rsum += __shfl_xor(rsum, 32, 64);

    const int bb = t & 1;
    if (l < 16) part[bb][v][r_mine] = rsum;
    // raw barrier: drain LDS only; poll leftovers stay in flight (they retarget LDS,
    // no register hazard; in-order retirement keeps next step's vmcnt counts exact)
    asm volatile("s_waitcnt lgkmcnt(0)" ::: "memory");
    __builtin_amdgcn_s_barrier();

    // distributed finalize (full-exec shuffles; only lanes 0,1 store).
    {
      float p = part[bb][(l >> 1) & 7][2 * v + (l & 1)];
      p += __shfl_xor(p, 2, 64);
      p += __shfl_xor(p, 4, 64);
      p += __shfl_xor(p, 8, 64);
      if (l < 2) {
        float pre = p + zbuf[v][l];
        float hn = 1.0f / (1.0f + __expf(-pre));
        // store IS the signal at the MALL
        __hip_atomic_store(hbuf + (long long)(t + 1) * HID + rowbase + 2 * v + l, hn,
                           __ATOMIC_RELAXED, __HIP_MEMORY_SCOPE_AGENT);
      }
    }
    // 'part' is double-buffered across t parity; the per-step barrier separates
    // step-t reads from step-t+2 writes.
  }
#undef FMAG
#undef GISSUE
#undef POLLCHK
#undef ALLD
}

// ---------------- K4: out = W_i2o @ [x_last, h_last] + b ----------------
__global__ __launch_bounds__(256) void k4_out(const float* __restrict__ X,
                                              const float* __restrict__ Wi2o,
                                              const float* __restrict__ bi2o,
                                              const float* __restrict__ hbuf,
                                              float* __restrict__ out) {
  const int v = threadIdx.x >> 6, l = threadIdx.x & 63;
  const int o = blockIdx.x * 4 + v;
  const float* wrow = Wi2o + (long long)o * CONCAT;
  const float* xlast = X + (long long)(SEQ - 1) * IN_DIM;
  const float* hlast = hbuf + (long long)(SEQ - 1) * HID;
  float s = 0.f;
  for (int k = l; k < IN_DIM; k += 64) s = fmaf(wrow[k], xlast[k], s);
  for (int k = l; k < HID; k += 64) s = fmaf(wrow[IN_DIM + k], hlast[k], s);
#pragma unroll
  for (int m = 1; m < 64; m <<= 1) s += __shfl_xor(s, m, 64);
  if (l == 0) out[o] = s + bi2o[o];
}

extern "C" void kernel_launch(void* const* d_in, const int* in_sizes, int n_in,
                              void* d_out, int out_size, void* d_ws, size_t ws_size,
                              hipStream_t stream) {
  (void)in_sizes; (void)n_in; (void)out_size; (void)ws_size;
  const float* X    = (const float*)d_in[0];
  const float* Wi2h = (const float*)d_in[1];
  const float* bi2h = (const float*)d_in[2];
  const float* Wi2o = (const float*)d_in[3];
  const float* bi2o = (const float*)d_in[4];
  float* out = (float*)d_out;

  char* ws = (char*)d_ws;
  float* Z            = (float*)(ws);
  float* hbuf         = (float*)(ws + 33554432);
  __hip_bfloat16* Xb  = (__hip_bfloat16*)(ws + 33554432);  // overlaps hbuf (dead before memset)
  __hip_bfloat16* Wxb = (__hip_bfloat16*)(ws + 41943040);

  hipLaunchKernelGGL(k1_prep, dim3(2048), dim3(256), 0, stream, X, Wi2h, Xb, Wxb);
  hipLaunchKernelGGL(k2_zgemm, dim3(2048), dim3(256), 0, stream, Xb, Wxb, bi2h, Z);

  // re-arm the data-as-flag sentinel every launch (graph-capture safe, stream-ordered)
  hipMemsetAsync(hbuf, 0xFF, 33554432, stream);

  void* args[] = { (void*)&Wi2h, (void*)&Z, (void*)&hbuf };
  hipLaunchCooperativeKernel((void*)k3_rnn, dim3(256), dim3(512), args, 0, stream);

  hipLaunchKernelGGL(k4_out, dim3(512), dim3(256), 0, stream, X, Wi2o, bi2o, hbuf, out);
}

// Round 12
// 8175.497 us; speedup vs baseline: 1.3120x; 1.3120x over previous
//
#include <hip/hip_runtime.h>
#include <hip/hip_bf16.h>
#include <stdint.h>

#define SEQ 2048
#define IN_DIM 2048
#define HID 4096
#define CONCAT 6144
#define OUT_DIM 2048

typedef __attribute__((ext_vector_type(8))) short s8v;
typedef __attribute__((ext_vector_type(4))) float f4v;

#define SENT 0xFFFFFFFFu   // sentinel; sigmoid output in (0,1) never matches
#define ROT_BUDGET 20000   // bounded rotations: fail loud (absmax), never hang

// ---------------- ws layout (bytes) ----------------
// Z:     [0, 33554432)            float Z[SEQ][HID]
// hbuf:  [33554432, 67108864)     float hbuf[SEQ][HID]   (rows 1..2047 used)
// Xb:    [33554432, +8388608)     bf16  (overlaps hbuf; dead before memset re-arms sentinel)
// Wxb:   [41943040, +16777216)    bf16
// total required: 67,108,864 B

// ---------------- K1: pack bf16 ----------------
__global__ __launch_bounds__(256) void k1_prep(const float* __restrict__ X,
                                               const float* __restrict__ Wi2h,
                                               __hip_bfloat16* __restrict__ Xb,
                                               __hip_bfloat16* __restrict__ Wxb) {
  int gid = blockIdx.x * blockDim.x + threadIdx.x;
  int stride = gridDim.x * blockDim.x;
  for (int i = gid; i < SEQ * IN_DIM; i += stride)
    Xb[i] = __float2bfloat16(X[i]);
  for (int i = gid; i < HID * IN_DIM; i += stride) {
    int r = i >> 11, c = i & (IN_DIM - 1);
    Wxb[i] = __float2bfloat16(Wi2h[(long long)r * CONCAT + c]);
  }
}

// ---------------- K2: Z = Xb @ Wxb^T + b  (bf16 MFMA, 64x64 tiles) ----------------
__global__ __launch_bounds__(256) void k2_zgemm(const __hip_bfloat16* __restrict__ Xb,
                                                const __hip_bfloat16* __restrict__ Wxb,
                                                const float* __restrict__ bias,
                                                float* __restrict__ Z) {
  __shared__ __align__(16) __hip_bfloat16 As[64][40];
  __shared__ __align__(16) __hip_bfloat16 Bs[64][40];
  const int bm = blockIdx.x & 31;
  const int bn = blockIdx.x >> 5;
  const int tid = threadIdx.x;
  const int wv = tid >> 6, l = tid & 63;
  const int wr = (wv >> 1) * 32, wc = (wv & 1) * 32;
  const int fr = l & 15, fko = (l >> 4) * 8;

  f4v acc[2][2] = {};
  const int r = tid >> 2, cc = (tid & 3) * 8;
  const __hip_bfloat16* ga = Xb + (long long)(bm * 64 + r) * IN_DIM + cc;
  const __hip_bfloat16* gb = Wxb + (long long)(bn * 64 + r) * IN_DIM + cc;

  for (int k0 = 0; k0 < IN_DIM; k0 += 32) {
    *(s8v*)&As[r][cc] = *(const s8v*)(ga + k0);
    *(s8v*)&Bs[r][cc] = *(const s8v*)(gb + k0);
    __syncthreads();
    s8v a0 = *(const s8v*)&As[wr + fr][fko];
    s8v a1 = *(const s8v*)&As[wr + 16 + fr][fko];
    s8v b0 = *(const s8v*)&Bs[wc + fr][fko];
    s8v b1 = *(const s8v*)&Bs[wc + 16 + fr][fko];
    acc[0][0] = __builtin_amdgcn_mfma_f32_16x16x32_bf16(a0, b0, acc[0][0], 0, 0, 0);
    acc[0][1] = __builtin_amdgcn_mfma_f32_16x16x32_bf16(a0, b1, acc[0][1], 0, 0, 0);
    acc[1][0] = __builtin_amdgcn_mfma_f32_16x16x32_bf16(a1, b0, acc[1][0], 0, 0, 0);
    acc[1][1] = __builtin_amdgcn_mfma_f32_16x16x32_bf16(a1, b1, acc[1][1], 0, 0, 0);
    __syncthreads();
  }
#pragma unroll
  for (int fm = 0; fm < 2; ++fm)
#pragma unroll
    for (int fn = 0; fn < 2; ++fn)
#pragma unroll
      for (int i = 0; i < 4; ++i) {
        int row = bm * 64 + wr + fm * 16 + (l >> 4) * 4 + i;
        int col = bn * 64 + wc + fn * 16 + fr;
        Z[(long long)row * HID + col] = acc[fm][fn][i] + bias[col];
      }
}

// ---------------- K3: persistent-weight recurrence (cooperative) ----------------
// 256 WGs x 512 thr. WG w owns h rows [16w,16w+16). Wave v owns K-slice [512v,512(v+1)).
// Lane l: k = 512v + 64j + l (j=0..7); weights Wreg[16][8] pinned.
// Sync: DATA-AS-FLAG at the MALL. Poll = 3 phase-shifted batches (A,B,C) of 8
// relaxed agent atomic loads, all in PLAIN C SSA form: the compiler owns the async
// registers and emits the counted s_waitcnt (in-order VMEM => checking A after
// issuing A,B,C waits ~vmcnt(16)), with correct lifetimes. This is R9's counted-
// vmcnt pipeline without the asm register hazard (R9 bug: compiler phi-copied
// asm-load dest regs while in flight) and without R10's LDS round trip + scattered
// finalize (4x write amplification). Resample spacing ~RT/3. Incremental per-group
// FMA on detection; conditional re-issue (done groups stop polling).
__global__ __launch_bounds__(512, 1) void k3_rnn(const float* __restrict__ Wi2h,
                                                 const float* __restrict__ Z,
                                                 float* __restrict__ hbuf) {
  const int w = blockIdx.x;
  const int tid = threadIdx.x;
  const int v = tid >> 6;
  const int l = tid & 63;
  const int rowbase = w * 16;
  const int kbase = v * 512 + l;

  float Wreg[16][8];
#pragma unroll
  for (int r = 0; r < 16; ++r) {
    const float* src = Wi2h + (long long)(rowbase + r) * CONCAT + IN_DIM + kbase;
#pragma unroll
    for (int j = 0; j < 8; ++j) Wreg[r][j] = src[64 * j];
  }
#pragma unroll
  for (int r = 0; r < 16; ++r)
#pragma unroll
    for (int j = 0; j < 8; ++j)
      asm volatile("" : "+v"(Wreg[r][j]));  // pin: no remat/sink into t-loop

  __shared__ float part[2][8][16];
  const int lm = l & 15;
  const int r_mine = ((lm & 1) << 3) | ((lm & 2) << 1) | ((lm & 4) >> 1) | ((lm & 8) >> 3);

#define LOADG(X, jj)                                                              \
  if (!d##jj) X[jj] = __hip_atomic_load(hrow + 64 * jj, __ATOMIC_RELAXED,         \
                                        __HIP_MEMORY_SCOPE_AGENT);

#define LOADB(X)                                                                  \
  LOADG(X, 0) LOADG(X, 1) LOADG(X, 2) LOADG(X, 3)                                 \
  LOADG(X, 4) LOADG(X, 5) LOADG(X, 6) LOADG(X, 7)

#define FMAG(uu, dd, jj)                                                          \
  if (!dd && __all((uu) != SENT)) {                                               \
    float h_ = __builtin_bit_cast(float, (uu));                                   \
    _Pragma("unroll")                                                             \
    for (int r = 0; r < 16; ++r) acc[r] = fmaf(Wreg[r][jj], h_, acc[r]);          \
    dd = true;                                                                    \
  }

#define CHECKB(X)                                                                 \
  FMAG(X[0], d0, 0) FMAG(X[1], d1, 1) FMAG(X[2], d2, 2) FMAG(X[3], d3, 3)         \
  FMAG(X[4], d4, 4) FMAG(X[5], d5, 5) FMAG(X[6], d6, 6) FMAG(X[7], d7, 7)

#define ALLD (d0 && d1 && d2 && d3 && d4 && d5 && d6 && d7)

#pragma clang loop unroll(disable)
  for (int t = 0; t < SEQ - 1; ++t) {
    // prefetch z for this WG's rows (independent of h)
    float zv = 0.f;
    if (v == 0 && l < 16) zv = Z[(long long)t * HID + rowbase + l];

    float acc[16];
#pragma unroll
    for (int r = 0; r < 16; ++r) acc[r] = 0.f;

    if (t > 0) {
      const uint32_t* hrow = (const uint32_t*)hbuf + (long long)t * HID + kbase;
      bool d0 = false, d1 = false, d2 = false, d3 = false,
           d4 = false, d5 = false, d6 = false, d7 = false;
      uint32_t XA[8], XB[8], XC[8];
      LOADB(XA) LOADB(XB) LOADB(XC)   // 24 loads in flight (compiler-tracked)
      int rot = 0;
      for (;;) {
        CHECKB(XA)                     // compiler waits ~vmcnt(16): B,C stay in flight
        if (ALLD) break;
        LOADB(XA)
        CHECKB(XB)
        if (ALLD) break;
        LOADB(XB)
        CHECKB(XC)
        if (ALLD) break;
        LOADB(XC)
        if (++rot > ROT_BUDGET) break; // fail loud (absmax), never hang
      }
      // leftover in-flight loads drain at __syncthreads below (same as R8)
    }

    // reduce-scatter butterfly: 16 accs across 64 lanes -> 1 row-sum per lane-of-16
#pragma unroll
    for (int i = 0; i < 8; ++i) {
      float send = (l & 1) ? acc[i] : acc[i + 8];
      float keep = (l & 1) ? acc[i + 8] : acc[i];
      acc[i] = keep + __shfl_xor(send, 1, 64);
    }
#pragma unroll
    for (int i = 0; i < 4; ++i) {
      float send = (l & 2) ? acc[i] : acc[i + 4];
      float keep = (l & 2) ? acc[i + 4] : acc[i];
      acc[i] = keep + __shfl_xor(send, 2, 64);
    }
#pragma unroll
    for (int i = 0; i < 2; ++i) {
      float send = (l & 4) ? acc[i] : acc[i + 2];
      float keep = (l & 4) ? acc[i + 2] : acc[i];
      acc[i] = keep + __shfl_xor(send, 4, 64);
    }
    {
      float send = (l & 8) ? acc[0] : acc[1];
      float keep = (l & 8) ? acc[1] : acc[0];
      acc[0] = keep + __shfl_xor(send, 8, 64);
    }
    float rsum = acc[0];
    rsum += __shfl_xor(rsum, 16, 64);
    rsum += __shfl_xor(rsum, 32, 64);

    const int b = t & 1;
    if (l < 16) part[b][v][r_mine] = rsum;
    __syncthreads();

    if (v == 0 && l < 16) {
      float s = 0.f;
#pragma unroll
      for (int q = 0; q < 8; ++q) s += part[b][q][l];
      float pre = s + zv;
      float hn = 1.0f / (1.0f + __expf(-pre));
      // store IS the signal — single wave => one coalesced 64B MALL transaction
      __hip_atomic_store(hbuf + (long long)(t + 1) * HID + rowbase + l, hn,
                         __ATOMIC_RELAXED, __HIP_MEMORY_SCOPE_AGENT);
    }
    // no second __syncthreads: 'part' is double-buffered across t parity
  }
#undef LOADG
#undef LOADB
#undef FMAG
#undef CHECKB
#undef ALLD
}

// ---------------- K4: out = W_i2o @ [x_last, h_last] + b ----------------
__global__ __launch_bounds__(256) void k4_out(const float* __restrict__ X,
                                              const float* __restrict__ Wi2o,
                                              const float* __restrict__ bi2o,
                                              const float* __restrict__ hbuf,
                                              float* __restrict__ out) {
  const int v = threadIdx.x >> 6, l = threadIdx.x & 63;
  const int o = blockIdx.x * 4 + v;
  const float* wrow = Wi2o + (long long)o * CONCAT;
  const float* xlast = X + (long long)(SEQ - 1) * IN_DIM;
  const float* hlast = hbuf + (long long)(SEQ - 1) * HID;
  float s = 0.f;
  for (int k = l; k < IN_DIM; k += 64) s = fmaf(wrow[k], xlast[k], s);
  for (int k = l; k < HID; k += 64) s = fmaf(wrow[IN_DIM + k], hlast[k], s);
#pragma unroll
  for (int m = 1; m < 64; m <<= 1) s += __shfl_xor(s, m, 64);
  if (l == 0) out[o] = s + bi2o[o];
}

extern "C" void kernel_launch(void* const* d_in, const int* in_sizes, int n_in,
                              void* d_out, int out_size, void* d_ws, size_t ws_size,
                              hipStream_t stream) {
  (void)in_sizes; (void)n_in; (void)out_size; (void)ws_size;
  const float* X    = (const float*)d_in[0];
  const float* Wi2h = (const float*)d_in[1];
  const float* bi2h = (const float*)d_in[2];
  const float* Wi2o = (const float*)d_in[3];
  const float* bi2o = (const float*)d_in[4];
  float* out = (float*)d_out;

  char* ws = (char*)d_ws;
  float* Z            = (float*)(ws);
  float* hbuf         = (float*)(ws + 33554432);
  __hip_bfloat16* Xb  = (__hip_bfloat16*)(ws + 33554432);  // overlaps hbuf (dead before memset)
  __hip_bfloat16* Wxb = (__hip_bfloat16*)(ws + 41943040);

  hipLaunchKernelGGL(k1_prep, dim3(2048), dim3(256), 0, stream, X, Wi2h, Xb, Wxb);
  hipLaunchKernelGGL(k2_zgemm, dim3(2048), dim3(256), 0, stream, Xb, Wxb, bi2h, Z);

  // re-arm the data-as-flag sentinel every launch (graph-capture safe, stream-ordered)
  hipMemsetAsync(hbuf, 0xFF, 33554432, stream);

  void* args[] = { (void*)&Wi2h, (void*)&Z, (void*)&hbuf };
  hipLaunchCooperativeKernel((void*)k3_rnn, dim3(256), dim3(512), args, 0, stream);

  hipLaunchKernelGGL(k4_out, dim3(512), dim3(256), 0, stream, X, Wi2o, bi2o, hbuf, out);
}

// Round 14
// 6534.334 us; speedup vs baseline: 1.6415x; 1.2512x over previous
//
#include <hip/hip_runtime.h>
#include <hip/hip_bf16.h>
#include <stdint.h>

#define SEQ 2048
#define IN_DIM 2048
#define HID 4096
#define CONCAT 6144
#define OUT_DIM 2048

typedef __attribute__((ext_vector_type(8))) short s8v;
typedef __attribute__((ext_vector_type(4))) float f4v;

#define SENT 0xFFFFFFFFu   // sentinel; sigmoid output in (0,1) never matches
#define ROT_BUDGET 20000   // bounded rotations: fail loud (absmax), never hang

// ---------------- ws layout (bytes) ----------------
// Z:     [0, 33554432)            float Z[SEQ][HID]
// hbuf:  [33554432, 67108864)     float hbuf[SEQ][HID]   (rows 1..2047 used)
// Xb:    [33554432, +8388608)     bf16  (overlaps hbuf; dead before memset re-arms sentinel)
// Wxb:   [41943040, +16777216)    bf16
// total required: 67,108,864 B

// ---------------- K1: pack bf16 ----------------
__global__ __launch_bounds__(256) void k1_prep(const float* __restrict__ X,
                                               const float* __restrict__ Wi2h,
                                               __hip_bfloat16* __restrict__ Xb,
                                               __hip_bfloat16* __restrict__ Wxb) {
  int gid = blockIdx.x * blockDim.x + threadIdx.x;
  int stride = gridDim.x * blockDim.x;
  for (int i = gid; i < SEQ * IN_DIM; i += stride)
    Xb[i] = __float2bfloat16(X[i]);
  for (int i = gid; i < HID * IN_DIM; i += stride) {
    int r = i >> 11, c = i & (IN_DIM - 1);
    Wxb[i] = __float2bfloat16(Wi2h[(long long)r * CONCAT + c]);
  }
}

// ---------------- K2: Z = Xb @ Wxb^T + b  (bf16 MFMA, 64x64 tiles) ----------------
__global__ __launch_bounds__(256) void k2_zgemm(const __hip_bfloat16* __restrict__ Xb,
                                                const __hip_bfloat16* __restrict__ Wxb,
                                                const float* __restrict__ bias,
                                                float* __restrict__ Z) {
  __shared__ __align__(16) __hip_bfloat16 As[64][40];
  __shared__ __align__(16) __hip_bfloat16 Bs[64][40];
  const int bm = blockIdx.x & 31;
  const int bn = blockIdx.x >> 5;
  const int tid = threadIdx.x;
  const int wv = tid >> 6, l = tid & 63;
  const int wr = (wv >> 1) * 32, wc = (wv & 1) * 32;
  const int fr = l & 15, fko = (l >> 4) * 8;

  f4v acc[2][2] = {};
  const int r = tid >> 2, cc = (tid & 3) * 8;
  const __hip_bfloat16* ga = Xb + (long long)(bm * 64 + r) * IN_DIM + cc;
  const __hip_bfloat16* gb = Wxb + (long long)(bn * 64 + r) * IN_DIM + cc;

  for (int k0 = 0; k0 < IN_DIM; k0 += 32) {
    *(s8v*)&As[r][cc] = *(const s8v*)(ga + k0);
    *(s8v*)&Bs[r][cc] = *(const s8v*)(gb + k0);
    __syncthreads();
    s8v a0 = *(const s8v*)&As[wr + fr][fko];
    s8v a1 = *(const s8v*)&As[wr + 16 + fr][fko];
    s8v b0 = *(const s8v*)&Bs[wc + fr][fko];
    s8v b1 = *(const s8v*)&Bs[wc + 16 + fr][fko];
    acc[0][0] = __builtin_amdgcn_mfma_f32_16x16x32_bf16(a0, b0, acc[0][0], 0, 0, 0);
    acc[0][1] = __builtin_amdgcn_mfma_f32_16x16x32_bf16(a0, b1, acc[0][1], 0, 0, 0);
    acc[1][0] = __builtin_amdgcn_mfma_f32_16x16x32_bf16(a1, b0, acc[1][0], 0, 0, 0);
    acc[1][1] = __builtin_amdgcn_mfma_f32_16x16x32_bf16(a1, b1, acc[1][1], 0, 0, 0);
    __syncthreads();
  }
#pragma unroll
  for (int fm = 0; fm < 2; ++fm)
#pragma unroll
    for (int fn = 0; fn < 2; ++fn)
#pragma unroll
      for (int i = 0; i < 4; ++i) {
        int row = bm * 64 + wr + fm * 16 + (l >> 4) * 4 + i;
        int col = bn * 64 + wc + fn * 16 + fr;
        Z[(long long)row * HID + col] = acc[fm][fn][i] + bias[col];
      }
}

// ---------------- K3: persistent-weight recurrence (cooperative) ----------------
// 256 WGs x 512 thr. WG w owns h rows [16w,16w+16). Wave v owns K-slice [512v,512(v+1)).
// Lane l: k = 512v + 64j + l (j=0..7); weights Wreg[16][8] pinned.
// Sync: DATA-AS-FLAG at the MALL (relaxed agent atomics). Poll = 2 phase-shifted
// UNCONDITIONAL batches (A,B) of 8 loads in plain C. No control flow touches issue
// or read: every slot is reloaded and its __all() freshness computed every pass
// (forces the compiler's counted cascade wait — checking A with B's 8 in flight
// waits ~vmcnt(15..8), NOT vmcnt(0)); the FMA alone is gated by done-flags.
// R12's regression isolated to conditional loads => conservative waits; fixed here.
// Sample period ~RT/2. Exit leaves <=8 unread in-flight loads => barrier must NOT
// drain vmcnt: raw s_waitcnt lgkmcnt(0) + s_barrier (m201 pattern) instead of
// __syncthreads; compiler guards any register reuse of in-flight dests itself.
__global__ __launch_bounds__(512, 1) void k3_rnn(const float* __restrict__ Wi2h,
                                                 const float* __restrict__ Z,
                                                 float* __restrict__ hbuf) {
  const int w = blockIdx.x;
  const int tid = threadIdx.x;
  const int v = tid >> 6;
  const int l = tid & 63;
  const int rowbase = w * 16;
  const int kbase = v * 512 + l;

  float Wreg[16][8];
#pragma unroll
  for (int r = 0; r < 16; ++r) {
    const float* src = Wi2h + (long long)(rowbase + r) * CONCAT + IN_DIM + kbase;
#pragma unroll
    for (int j = 0; j < 8; ++j) Wreg[r][j] = src[64 * j];
  }
#pragma unroll
  for (int r = 0; r < 16; ++r)
#pragma unroll
    for (int j = 0; j < 8; ++j)
      asm volatile("" : "+v"(Wreg[r][j]));  // pin: no remat/sink into t-loop

  __shared__ float part[2][8][16];
  const int lm = l & 15;
  const int r_mine = ((lm & 1) << 3) | ((lm & 2) << 1) | ((lm & 4) >> 1) | ((lm & 8) >> 3);

#define LOADB(X)                                                                  \
  _Pragma("unroll")                                                               \
  for (int j = 0; j < 8; ++j)                                                     \
    X[j] = __hip_atomic_load(hrow + 64 * j, __ATOMIC_RELAXED,                     \
                             __HIP_MEMORY_SCOPE_AGENT);

#define FMAG(uu, dd, jj)                                                          \
  {                                                                               \
    bool fresh_ = __all((uu) != SENT); /* unconditional read: forces counted wait */ \
    if (!dd && fresh_) {                                                          \
      float h_ = __builtin_bit_cast(float, (uu));                                 \
      _Pragma("unroll")                                                           \
      for (int r = 0; r < 16; ++r) acc[r] = fmaf(Wreg[r][jj], h_, acc[r]);        \
      dd = true;                                                                  \
    }                                                                             \
  }

#define CHECKB(X)                                                                 \
  FMAG(X[0], d0, 0) FMAG(X[1], d1, 1) FMAG(X[2], d2, 2) FMAG(X[3], d3, 3)         \
  FMAG(X[4], d4, 4) FMAG(X[5], d5, 5) FMAG(X[6], d6, 6) FMAG(X[7], d7, 7)

#define ALLD (d0 && d1 && d2 && d3 && d4 && d5 && d6 && d7)

#pragma clang loop unroll(disable)
  for (int t = 0; t < SEQ - 1; ++t) {
    // prefetch z for this WG's rows (independent of h; retires before polls matter)
    float zv = 0.f;
    if (v == 0 && l < 16) zv = Z[(long long)t * HID + rowbase + l];

    float acc[16];
#pragma unroll
    for (int r = 0; r < 16; ++r) acc[r] = 0.f;

    if (t > 0) {
      const uint32_t* hrow = (const uint32_t*)hbuf + (long long)t * HID + kbase;
      bool d0 = false, d1 = false, d2 = false, d3 = false,
           d4 = false, d5 = false, d6 = false, d7 = false;
      uint32_t XA[8], XB[8];
      LOADB(XA) LOADB(XB)              // 16 in flight, straight-line
      int rot = 0;
      for (;;) {
        CHECKB(XA)                     // waits ~vmcnt(15..8): B stays in flight
        if (ALLD) break;
        LOADB(XA)
        CHECKB(XB)
        if (ALLD) break;
        LOADB(XB)
        if (++rot > ROT_BUDGET) break; // fail loud (absmax), never hang
      }
      // <=8 unread loads may remain in flight; raw barrier below does NOT drain them
    }

    // reduce-scatter butterfly: 16 accs across 64 lanes -> 1 row-sum per lane-of-16
#pragma unroll
    for (int i = 0; i < 8; ++i) {
      float send = (l & 1) ? acc[i] : acc[i + 8];
      float keep = (l & 1) ? acc[i + 8] : acc[i];
      acc[i] = keep + __shfl_xor(send, 1, 64);
    }
#pragma unroll
    for (int i = 0; i < 4; ++i) {
      float send = (l & 2) ? acc[i] : acc[i + 4];
      float keep = (l & 2) ? acc[i + 4] : acc[i];
      acc[i] = keep + __shfl_xor(send, 2, 64);
    }
#pragma unroll
    for (int i = 0; i < 2; ++i) {
      float send = (l & 4) ? acc[i] : acc[i + 2];
      float keep = (l & 4) ? acc[i + 2] : acc[i];
      acc[i] = keep + __shfl_xor(send, 4, 64);
    }
    {
      float send = (l & 8) ? acc[0] : acc[1];
      float keep = (l & 8) ? acc[1] : acc[0];
      acc[0] = keep + __shfl_xor(send, 8, 64);
    }
    float rsum = acc[0];
    rsum += __shfl_xor(rsum, 16, 64);
    rsum += __shfl_xor(rsum, 32, 64);

    const int b = t & 1;
    if (l < 16) part[b][v][r_mine] = rsum;
    // raw barrier: LDS ordering only (lgkmcnt), NO vmcnt drain of in-flight polls
    asm volatile("s_waitcnt lgkmcnt(0)" ::: "memory");
    __builtin_amdgcn_s_barrier();

    if (v == 0 && l < 16) {
      float s = 0.f;
#pragma unroll
      for (int q = 0; q < 8; ++q) s += part[b][q][l];
      float pre = s + zv;
      float hn = 1.0f / (1.0f + __expf(-pre));
      // store IS the signal — single wave => one coalesced 64B MALL transaction
      __hip_atomic_store(hbuf + (long long)(t + 1) * HID + rowbase + l, hn,
                         __ATOMIC_RELAXED, __HIP_MEMORY_SCOPE_AGENT);
    }
    // 'part' is double-buffered across t parity; one barrier/step suffices
    // (a wave cannot be two barriers ahead of wave 0's LDS reads)
  }
#undef LOADB
#undef FMAG
#undef CHECKB
#undef ALLD
}

// ---------------- K4: out = W_i2o @ [x_last, h_last] + b ----------------
__global__ __launch_bounds__(256) void k4_out(const float* __restrict__ X,
                                              const float* __restrict__ Wi2o,
                                              const float* __restrict__ bi2o,
                                              const float* __restrict__ hbuf,
                                              float* __restrict__ out) {
  const int v = threadIdx.x >> 6, l = threadIdx.x & 63;
  const int o = blockIdx.x * 4 + v;
  const float* wrow = Wi2o + (long long)o * CONCAT;
  const float* xlast = X + (long long)(SEQ - 1) * IN_DIM;
  const float* hlast = hbuf + (long long)(SEQ - 1) * HID;
  float s = 0.f;
  for (int k = l; k < IN_DIM; k += 64) s = fmaf(wrow[k], xlast[k], s);
  for (int k = l; k < HID; k += 64) s = fmaf(wrow[IN_DIM + k], hlast[k], s);
#pragma unroll
  for (int m = 1; m < 64; m <<= 1) s += __shfl_xor(s, m, 64);
  if (l == 0) out[o] = s + bi2o[o];
}

extern "C" void kernel_launch(void* const* d_in, const int* in_sizes, int n_in,
                              void* d_out, int out_size, void* d_ws, size_t ws_size,
                              hipStream_t stream) {
  (void)in_sizes; (void)n_in; (void)out_size; (void)ws_size;
  const float* X    = (const float*)d_in[0];
  const float* Wi2h = (const float*)d_in[1];
  const float* bi2h = (const float*)d_in[2];
  const float* Wi2o = (const float*)d_in[3];
  const float* bi2o = (const float*)d_in[4];
  float* out = (float*)d_out;

  char* ws = (char*)d_ws;
  float* Z            = (float*)(ws);
  float* hbuf         = (float*)(ws + 33554432);
  __hip_bfloat16* Xb  = (__hip_bfloat16*)(ws + 33554432);  // overlaps hbuf (dead before memset)
  __hip_bfloat16* Wxb = (__hip_bfloat16*)(ws + 41943040);

  hipLaunchKernelGGL(k1_prep, dim3(2048), dim3(256), 0, stream, X, Wi2h, Xb, Wxb);
  hipLaunchKernelGGL(k2_zgemm, dim3(2048), dim3(256), 0, stream, Xb, Wxb, bi2h, Z);

  // re-arm the data-as-flag sentinel every launch (graph-capture safe, stream-ordered)
  hipMemsetAsync(hbuf, 0xFF, 33554432, stream);

  void* args[] = { (void*)&Wi2h, (void*)&Z, (void*)&hbuf };
  hipLaunchCooperativeKernel((void*)k3_rnn, dim3(256), dim3(512), args, 0, stream);

  hipLaunchKernelGGL(k4_out, dim3(512), dim3(256), 0, stream, X, Wi2o, bi2o, hbuf, out);
}

// Round 15
// 5622.776 us; speedup vs baseline: 1.9076x; 1.1621x over previous
//
#include <hip/hip_runtime.h>
#include <hip/hip_bf16.h>
#include <stdint.h>

#define SEQ 2048
#define IN_DIM 2048
#define HID 4096
#define CONCAT 6144
#define OUT_DIM 2048

typedef __attribute__((ext_vector_type(8))) short s8v;
typedef __attribute__((ext_vector_type(4))) float f4v;

#define SENT 0xFFFFFFFFu   // sentinel; sigmoid output in (0,1) never matches
#define SPIN_BUDGET 20000  // ~14 ms/step worst case: fail loud (absmax), not hang

// ---------------- ws layout (bytes) ----------------
// Z:     [0, 33554432)            float Z[SEQ][HID]
// hbuf:  [33554432, 67108864)     float hbuf[SEQ][HID]   (rows 1..2047 used)
// Xb:    [33554432, +8388608)     bf16  (overlaps hbuf; dead before memset re-arms sentinel)
// Wxb:   [41943040, +16777216)    bf16
// total required: 67,108,864 B

// ---------------- K1: pack bf16 ----------------
__global__ __launch_bounds__(256) void k1_prep(const float* __restrict__ X,
                                               const float* __restrict__ Wi2h,
                                               __hip_bfloat16* __restrict__ Xb,
                                               __hip_bfloat16* __restrict__ Wxb) {
  int gid = blockIdx.x * blockDim.x + threadIdx.x;
  int stride = gridDim.x * blockDim.x;
  for (int i = gid; i < SEQ * IN_DIM; i += stride)
    Xb[i] = __float2bfloat16(X[i]);
  for (int i = gid; i < HID * IN_DIM; i += stride) {
    int r = i >> 11, c = i & (IN_DIM - 1);
    Wxb[i] = __float2bfloat16(Wi2h[(long long)r * CONCAT + c]);
  }
}

// ---------------- K2: Z = Xb @ Wxb^T + b  (bf16 MFMA, 64x64 tiles) ----------------
__global__ __launch_bounds__(256) void k2_zgemm(const __hip_bfloat16* __restrict__ Xb,
                                                const __hip_bfloat16* __restrict__ Wxb,
                                                const float* __restrict__ bias,
                                                float* __restrict__ Z) {
  __shared__ __align__(16) __hip_bfloat16 As[64][40];  // +8 pad: kills ds_read conflicts
  __shared__ __align__(16) __hip_bfloat16 Bs[64][40];
  const int bm = blockIdx.x & 31;   // 32 M-tiles (SEQ/64)
  const int bn = blockIdx.x >> 5;   // 64 N-tiles (HID/64)
  const int tid = threadIdx.x;
  const int wv = tid >> 6, l = tid & 63;
  const int wr = (wv >> 1) * 32, wc = (wv & 1) * 32;   // wave's 32x32 quadrant
  const int fr = l & 15, fko = (l >> 4) * 8;

  f4v acc[2][2] = {};
  const int r = tid >> 2, cc = (tid & 3) * 8;          // staging: row, 8-elem chunk
  const __hip_bfloat16* ga = Xb + (long long)(bm * 64 + r) * IN_DIM + cc;
  const __hip_bfloat16* gb = Wxb + (long long)(bn * 64 + r) * IN_DIM + cc;

  for (int k0 = 0; k0 < IN_DIM; k0 += 32) {
    *(s8v*)&As[r][cc] = *(const s8v*)(ga + k0);
    *(s8v*)&Bs[r][cc] = *(const s8v*)(gb + k0);
    __syncthreads();
    s8v a0 = *(const s8v*)&As[wr + fr][fko];
    s8v a1 = *(const s8v*)&As[wr + 16 + fr][fko];
    s8v b0 = *(const s8v*)&Bs[wc + fr][fko];
    s8v b1 = *(const s8v*)&Bs[wc + 16 + fr][fko];
    acc[0][0] = __builtin_amdgcn_mfma_f32_16x16x32_bf16(a0, b0, acc[0][0], 0, 0, 0);
    acc[0][1] = __builtin_amdgcn_mfma_f32_16x16x32_bf16(a0, b1, acc[0][1], 0, 0, 0);
    acc[1][0] = __builtin_amdgcn_mfma_f32_16x16x32_bf16(a1, b0, acc[1][0], 0, 0, 0);
    acc[1][1] = __builtin_amdgcn_mfma_f32_16x16x32_bf16(a1, b1, acc[1][1], 0, 0, 0);
    __syncthreads();
  }
#pragma unroll
  for (int fm = 0; fm < 2; ++fm)
#pragma unroll
    for (int fn = 0; fn < 2; ++fn)
#pragma unroll
      for (int i = 0; i < 4; ++i) {
        int row = bm * 64 + wr + fm * 16 + (l >> 4) * 4 + i;
        int col = bn * 64 + wc + fn * 16 + fr;
        Z[(long long)row * HID + col] = acc[fm][fn][i] + bias[col];
      }
}

// ---------------- K3: persistent-weight recurrence (cooperative) ----------------
// 256 WGs x 512 thr. WG w owns h rows [16w,16w+16). Wave v owns K-slice [512v,512(v+1)).
// Lane l: k = 512v + 64j + l (j=0..7); weights Wreg[16][8] pinned (AGPR-resident).
// Sync: DATA-AS-FLAG at the MALL (relaxed agent atomics, sc1). Consumers spin tight
// (no s_sleep); INCREMENTAL FMA: poll-group j depends on only 4 producer WGs; as soon
// as __all(got[j]) the group's 16 FMAs run (wave-uniform), overlapping later groups'
// detection. R12/R14 proved deeper poll pipelines regress (added VALU + issue traffic
// without beating the last-producer arrival time): this simple loop is the floor.
__global__ __launch_bounds__(512, 1) void k3_rnn(const float* __restrict__ Wi2h,
                                                 const float* __restrict__ Z,
                                                 float* __restrict__ hbuf) {
  const int w = blockIdx.x;
  const int tid = threadIdx.x;
  const int v = tid >> 6;
  const int l = tid & 63;
  const int rowbase = w * 16;
  const int kbase = v * 512 + l;

  float Wreg[16][8];
#pragma unroll
  for (int r = 0; r < 16; ++r) {
    const float* src = Wi2h + (long long)(rowbase + r) * CONCAT + IN_DIM + kbase;
#pragma unroll
    for (int j = 0; j < 8; ++j) Wreg[r][j] = src[64 * j];
  }
  // pin weights: opaque identity so the compiler can neither rematerialize from
  // memory nor sink the loads into the t-loop
#pragma unroll
  for (int r = 0; r < 16; ++r)
#pragma unroll
    for (int j = 0; j < 8; ++j)
      asm volatile("" : "+v"(Wreg[r][j]));

  __shared__ float part[2][8][16];
  const int lm = l & 15;
  const int r_mine = ((lm & 1) << 3) | ((lm & 2) << 1) | ((lm & 4) >> 1) | ((lm & 8) >> 3);

  for (int t = 0; t < SEQ - 1; ++t) {
    // prefetch z for this WG's rows (independent of h)
    float zv = 0.f;
    if (v == 0 && l < 16) zv = Z[(long long)t * HID + rowbase + l];

    float acc[16];
#pragma unroll
    for (int r = 0; r < 16; ++r) acc[r] = 0.f;

    if (t > 0) {
      // data-as-flag poll with incremental per-group FMA. Group j (one dword/lane,
      // rows 512v+64j .. +63) is produced by just 4 WGs -> completes early and its
      // FMAs overlap detection of the remaining groups.
      const uint32_t* hrow = (const uint32_t*)hbuf + (long long)t * HID + kbase;
      bool done[8];
#pragma unroll
      for (int j = 0; j < 8; ++j) done[j] = false;
      int spins = 0;
      while (true) {
        uint32_t uj[8];
#pragma unroll
        for (int j = 0; j < 8; ++j)
          if (!done[j])
            uj[j] = __hip_atomic_load(hrow + 64 * j, __ATOMIC_RELAXED, __HIP_MEMORY_SCOPE_AGENT);
        bool alldone = true;
#pragma unroll
        for (int j = 0; j < 8; ++j) {
          if (!done[j]) {
            if (__all(uj[j] != SENT)) {   // wave-uniform trigger
              float h = __builtin_bit_cast(float, uj[j]);
#pragma unroll
              for (int r = 0; r < 16; ++r)
                acc[r] = fmaf(Wreg[r][j], h, acc[r]);
              done[j] = true;
            } else {
              alldone = false;
            }
          }
        }
        if (alldone) break;
        if (++spins > SPIN_BUDGET) break;  // deadlock insurance: fail loud, not hang
      }
    }

    // reduce-scatter butterfly: 16 accs across 64 lanes -> 1 row-sum per lane-of-16
#pragma unroll
    for (int i = 0; i < 8; ++i) {
      float send = (l & 1) ? acc[i] : acc[i + 8];
      float keep = (l & 1) ? acc[i + 8] : acc[i];
      acc[i] = keep + __shfl_xor(send, 1, 64);
    }
#pragma unroll
    for (int i = 0; i < 4; ++i) {
      float send = (l & 2) ? acc[i] : acc[i + 4];
      float keep = (l & 2) ? acc[i + 4] : acc[i];
      acc[i] = keep + __shfl_xor(send, 2, 64);
    }
#pragma unroll
    for (int i = 0; i < 2; ++i) {
      float send = (l & 4) ? acc[i] : acc[i + 2];
      float keep = (l & 4) ? acc[i + 2] : acc[i];
      acc[i] = keep + __shfl_xor(send, 4, 64);
    }
    {
      float send = (l & 8) ? acc[0] : acc[1];
      float keep = (l & 8) ? acc[1] : acc[0];
      acc[0] = keep + __shfl_xor(send, 8, 64);
    }
    float rsum = acc[0];
    rsum += __shfl_xor(rsum, 16, 64);
    rsum += __shfl_xor(rsum, 32, 64);

    const int b = t & 1;
    if (l < 16) part[b][v][r_mine] = rsum;
    __syncthreads();

    if (v == 0 && l < 16) {
      float s = 0.f;
#pragma unroll
      for (int q = 0; q < 8; ++q) s += part[b][q][l];
      float pre = s + zv;
      float hn = 1.0f / (1.0f + __expf(-pre));
      // store IS the signal — single wave => one coalesced 64B MALL transaction
      __hip_atomic_store(hbuf + (long long)(t + 1) * HID + rowbase + l, hn,
                         __ATOMIC_RELAXED, __HIP_MEMORY_SCOPE_AGENT);
    }
    // no second __syncthreads: LDS 'part' is double-buffered; waves pipeline into
    // the next step's poll while wave 0 finalizes.
  }
}

// ---------------- K4: out = W_i2o @ [x_last, h_last] + b ----------------
__global__ __launch_bounds__(256) void k4_out(const float* __restrict__ X,
                                              const float* __restrict__ Wi2o,
                                              const float* __restrict__ bi2o,
                                              const float* __restrict__ hbuf,
                                              float* __restrict__ out) {
  const int v = threadIdx.x >> 6, l = threadIdx.x & 63;
  const int o = blockIdx.x * 4 + v;
  const float* wrow = Wi2o + (long long)o * CONCAT;
  const float* xlast = X + (long long)(SEQ - 1) * IN_DIM;
  const float* hlast = hbuf + (long long)(SEQ - 1) * HID;
  float s = 0.f;
  for (int k = l; k < IN_DIM; k += 64) s = fmaf(wrow[k], xlast[k], s);
  for (int k = l; k < HID; k += 64) s = fmaf(wrow[IN_DIM + k], hlast[k], s);
#pragma unroll
  for (int m = 1; m < 64; m <<= 1) s += __shfl_xor(s, m, 64);
  if (l == 0) out[o] = s + bi2o[o];
}

extern "C" void kernel_launch(void* const* d_in, const int* in_sizes, int n_in,
                              void* d_out, int out_size, void* d_ws, size_t ws_size,
                              hipStream_t stream) {
  (void)in_sizes; (void)n_in; (void)out_size; (void)ws_size;
  const float* X    = (const float*)d_in[0];
  const float* Wi2h = (const float*)d_in[1];
  const float* bi2h = (const float*)d_in[2];
  const float* Wi2o = (const float*)d_in[3];
  const float* bi2o = (const float*)d_in[4];
  float* out = (float*)d_out;

  char* ws = (char*)d_ws;
  float* Z            = (float*)(ws);
  float* hbuf         = (float*)(ws + 33554432);
  __hip_bfloat16* Xb  = (__hip_bfloat16*)(ws + 33554432);  // overlaps hbuf (dead before memset)
  __hip_bfloat16* Wxb = (__hip_bfloat16*)(ws + 41943040);

  hipLaunchKernelGGL(k1_prep, dim3(2048), dim3(256), 0, stream, X, Wi2h, Xb, Wxb);
  hipLaunchKernelGGL(k2_zgemm, dim3(2048), dim3(256), 0, stream, Xb, Wxb, bi2h, Z);

  // re-arm the data-as-flag sentinel every launch (graph-capture safe, stream-ordered)
  hipMemsetAsync(hbuf, 0xFF, 33554432, stream);

  void* args[] = { (void*)&Wi2h, (void*)&Z, (void*)&hbuf };
  hipLaunchCooperativeKernel((void*)k3_rnn, dim3(256), dim3(512), args, 0, stream);

  hipLaunchKernelGGL(k4_out, dim3(512), dim3(256), 0, stream, X, Wi2o, bi2o, hbuf, out);
}